// Round 1
// baseline (1142.267 us; speedup 1.0000x reference)
//
#include <hip/hip_runtime.h>
#include <math.h>

#define LMAX 360
#define MMAX 361
#define NLAT 361
#define NLON 720
#define BC   32
#define RTOT (BC*2*NLAT)  // 23104 rows of the irfft

// ---------------------------------------------------------------------------
// Stage 1: per-m GEMM over l.
//   srl = x0r*d0 - x1i*d1 ; sim = x0i*d0 + x1r*d1
//   trl = -x0i*d1 - x1r*d0; tim = x0r*d1 - x1i*d0
// Intermediate layout: inter[m][R] (float2 re,im), R = (bc*2 + t)*NLAT + k
// Block: (m, rowgroup of 8 bc). 384 threads, thread = k (k<361 active).
// ---------------------------------------------------------------------------
__global__ __launch_bounds__(384) void sht_stage1(
    const float* __restrict__ x, const float* __restrict__ dpct,
    float2* __restrict__ inter)
{
    const int m   = blockIdx.x;
    const int bc0 = blockIdx.y * 8;
    __shared__ __align__(16) float xls[8][LMAX][4];

    const float2* __restrict__ x2 = (const float2*)x;
    // Load 8 rows x 360 l x {f=0,f=1} float2 (re,im) pairs into LDS.
    // x flat float2 index: (((bc*2 + f)*LMAX + l)*MMAX + m)
    for (int i = threadIdx.x; i < 8 * LMAX * 2; i += 384) {
        int row = i / (LMAX * 2);
        int rem = i % (LMAX * 2);
        int f   = rem / LMAX;
        int l   = rem % LMAX;
        float2 v = x2[(((size_t)(bc0 + row) * 2 + f) * LMAX + l) * MMAX + m];
        xls[row][l][f * 2 + 0] = v.x;
        xls[row][l][f * 2 + 1] = v.y;
    }
    __syncthreads();

    const int k = threadIdx.x;
    if (k >= NLAT) return;

    float srl[8], sim[8], trl[8], tim[8];
    #pragma unroll
    for (int r = 0; r < 8; ++r) { srl[r] = 0.f; sim[r] = 0.f; trl[r] = 0.f; tim[r] = 0.f; }

    // dpct[p][m][l][k], flat = ((p*MMAX + m)*LMAX + l)*NLAT + k
    const float* __restrict__ dp0 = dpct + ((size_t)m * LMAX) * NLAT + k;
    const float* __restrict__ dp1 = dpct + ((size_t)(MMAX + m) * LMAX) * NLAT + k;

    #pragma unroll 2
    for (int l = 0; l < LMAX; ++l) {
        float d0v = dp0[(size_t)l * NLAT];
        float d1v = dp1[(size_t)l * NLAT];
        #pragma unroll
        for (int r = 0; r < 8; ++r) {
            float4 xv = *(const float4*)&xls[r][l][0];
            float x0r = xv.x, x0i = xv.y, x1r = xv.z, x1i = xv.w;
            srl[r] = fmaf(x0r, d0v, fmaf(-x1i, d1v, srl[r]));
            sim[r] = fmaf(x0i, d0v, fmaf( x1r, d1v, sim[r]));
            trl[r] = fmaf(-x0i, d1v, fmaf(-x1r, d0v, trl[r]));
            tim[r] = fmaf( x0r, d1v, fmaf(-x1i, d0v, tim[r]));
        }
    }

    #pragma unroll
    for (int r = 0; r < 8; ++r) {
        size_t Rs = ((size_t)(bc0 + r) * 2 + 0) * NLAT + k;   // t = 0 (s)
        size_t Rt = Rs + NLAT;                                // t = 1 (t)
        inter[(size_t)m * RTOT + Rs] = make_float2(srl[r], sim[r]);
        inter[(size_t)m * RTOT + Rt] = make_float2(trl[r], tim[r]);
    }
}

// ---------------------------------------------------------------------------
// Stage 2: inverse real DFT, n=720, forward norm (no 1/n):
//   out[j] = ReX0 + (-1)^j ReX360 + 2*sum_{m=1}^{359} (ReXm cos - ImXm sin)
// Pair trick: out[j+360] flips the sign of odd-m terms -> accumulate
// even/odd partial sums, emit 2 outputs per thread.
// Block: 16 rows (R0..R0+15), 128 threads over j (j<360 active).
// ---------------------------------------------------------------------------
__global__ __launch_bounds__(128) void sht_stage2(
    const float2* __restrict__ inter, float* __restrict__ out)
{
    const int R0 = blockIdx.y * 16;
    const int j  = blockIdx.x * 128 + threadIdx.x;
    __shared__ float2 xls[16][MMAX];

    for (int i = threadIdx.x; i < 16 * MMAX; i += 128) {
        int r  = i & 15;
        int mi = i >> 4;
        xls[r][mi] = inter[(size_t)mi * RTOT + R0 + r];
    }
    __syncthreads();

    if (j >= 360) return;

    float innerE[16], innerO[16];
    #pragma unroll
    for (int r = 0; r < 16; ++r) { innerE[r] = 0.f; innerO[r] = 0.f; }

    float sd, cd;
    __sincosf((float)(2.0 * M_PI / 720.0) * (float)j, &sd, &cd);

    float c1 = cd, s1 = sd;   // angle for m = 1
    for (int mo = 1; mo <= 359; mo += 2) {
        #pragma unroll
        for (int r = 0; r < 16; ++r) {
            float2 xv = xls[r][mo];
            innerO[r] += fmaf(xv.x, c1, -xv.y * s1);
        }
        float c2 = fmaf(c1, cd, -s1 * sd);   // m = mo+1
        float s2 = fmaf(s1, cd,  c1 * sd);
        if (mo + 1 <= 359) {
            #pragma unroll
            for (int r = 0; r < 16; ++r) {
                float2 xv = xls[r][mo + 1];
                innerE[r] += fmaf(xv.x, c2, -xv.y * s2);
            }
        }
        c1 = fmaf(c2, cd, -s2 * sd);         // m = mo+2
        s1 = fmaf(s2, cd,  c2 * sd);
    }

    const float sgn = (j & 1) ? -1.f : 1.f;
    #pragma unroll
    for (int r = 0; r < 16; ++r) {
        float base = xls[r][0].x + sgn * xls[r][360].x;  // m=0 and m=360 (Nyquist)
        float o0 = base + 2.f * (innerE[r] + innerO[r]);
        float o1 = base + 2.f * (innerE[r] - innerO[r]);
        out[(size_t)(R0 + r) * NLON + j]       = o0;
        out[(size_t)(R0 + r) * NLON + j + 360] = o1;
    }
}

// ---------------------------------------------------------------------------
extern "C" void kernel_launch(void* const* d_in, const int* in_sizes, int n_in,
                              void* d_out, int out_size, void* d_ws, size_t ws_size,
                              hipStream_t stream)
{
    const float* x    = (const float*)d_in[0];
    const float* dpct = (const float*)d_in[1];
    float* out        = (float*)d_out;
    float2* inter     = (float2*)d_ws;   // needs MMAX*RTOT*8 = 66.7 MB

    dim3 g1(MMAX, BC / 8);
    sht_stage1<<<g1, 384, 0, stream>>>(x, dpct, inter);

    dim3 g2(3, RTOT / 16);
    sht_stage2<<<g2, 128, 0, stream>>>(inter, out);
}

// Round 2
// 876.316 us; speedup vs baseline: 1.3035x; 1.3035x over previous
//
#include <hip/hip_runtime.h>
#include <hip/hip_bf16.h>
#include <math.h>

#define LMAX 360
#define MMAX 361
#define NLAT 361
#define NLON 720
#define BC   32
#define MT   (BC*2*NLAT)   // 23104 rows
#define QT   722           // valid K (2*MMAX)
#define KP   736           // padded K = 23*32
#define NP   768           // padded N = 6*128
#define BM   128
#define BN   128
#define BK   32

typedef __attribute__((ext_vector_type(8))) short short8;
typedef __attribute__((ext_vector_type(4))) float f32x4;

// ---------------------------------------------------------------------------
// Stage 1: per-m contraction over l (fp32 math), store bf16 planes
// interQ[q][R], q = 2m + (0:re / 1:im), R = (bc*2 + t)*NLAT + k
// ---------------------------------------------------------------------------
__global__ __launch_bounds__(384) void sht_stage1(
    const float* __restrict__ x, const float* __restrict__ dpct,
    __hip_bfloat16* __restrict__ interQ)
{
    const int m   = blockIdx.x;
    const int bc0 = blockIdx.y * 8;
    __shared__ __align__(16) float xls[8][LMAX][4];

    const float2* __restrict__ x2 = (const float2*)x;
    for (int i = threadIdx.x; i < 8 * LMAX * 2; i += 384) {
        int row = i / (LMAX * 2);
        int rem = i % (LMAX * 2);
        int f   = rem / LMAX;
        int l   = rem % LMAX;
        float2 v = x2[(((size_t)(bc0 + row) * 2 + f) * LMAX + l) * MMAX + m];
        xls[row][l][f * 2 + 0] = v.x;
        xls[row][l][f * 2 + 1] = v.y;
    }
    __syncthreads();

    const int k = threadIdx.x;
    if (k >= NLAT) return;

    float srl[8], sim[8], trl[8], tim[8];
    #pragma unroll
    for (int r = 0; r < 8; ++r) { srl[r] = 0.f; sim[r] = 0.f; trl[r] = 0.f; tim[r] = 0.f; }

    const float* __restrict__ dp0 = dpct + ((size_t)m * LMAX) * NLAT + k;
    const float* __restrict__ dp1 = dpct + ((size_t)(MMAX + m) * LMAX) * NLAT + k;

    #pragma unroll 2
    for (int l = 0; l < LMAX; ++l) {
        float d0v = dp0[(size_t)l * NLAT];
        float d1v = dp1[(size_t)l * NLAT];
        #pragma unroll
        for (int r = 0; r < 8; ++r) {
            float4 xv = *(const float4*)&xls[r][l][0];
            float x0r = xv.x, x0i = xv.y, x1r = xv.z, x1i = xv.w;
            srl[r] = fmaf(x0r, d0v, fmaf(-x1i, d1v, srl[r]));
            sim[r] = fmaf(x0i, d0v, fmaf( x1r, d1v, sim[r]));
            trl[r] = fmaf(-x0i, d1v, fmaf(-x1r, d0v, trl[r]));
            tim[r] = fmaf( x0r, d1v, fmaf(-x1i, d0v, tim[r]));
        }
    }

    const size_t qre = (size_t)(2 * m) * MT;
    const size_t qim = qre + MT;
    #pragma unroll
    for (int r = 0; r < 8; ++r) {
        size_t Rs = ((size_t)(bc0 + r) * 2 + 0) * NLAT + k;   // t = 0 (s)
        size_t Rt = Rs + NLAT;                                // t = 1 (t)
        interQ[qre + Rs] = __float2bfloat16(srl[r]);
        interQ[qim + Rs] = __float2bfloat16(sim[r]);
        interQ[qre + Rt] = __float2bfloat16(trl[r]);
        interQ[qim + Rt] = __float2bfloat16(tim[r]);
    }
}

// ---------------------------------------------------------------------------
// Transpose interQ [722][23104] -> interT [23104][736] (zero K-pad)
// ---------------------------------------------------------------------------
__global__ __launch_bounds__(256) void sht_transpose(
    const __hip_bfloat16* __restrict__ inQ, __hip_bfloat16* __restrict__ outT)
{
    __shared__ __hip_bfloat16 tile[64][65];
    const int R0 = blockIdx.x * 64;
    const int q0 = blockIdx.y * 64;
    const int tx = threadIdx.x & 63;
    const int ty = threadIdx.x >> 6;
    const __hip_bfloat16 zv = __float2bfloat16(0.f);

    for (int qq = ty; qq < 64; qq += 4) {
        int q = q0 + qq;
        tile[qq][tx] = (q < QT) ? inQ[(size_t)q * MT + R0 + tx] : zv;
    }
    __syncthreads();
    if (q0 + tx < KP) {
        for (int rr = ty; rr < 64; rr += 4) {
            outT[(size_t)(R0 + rr) * KP + q0 + tx] = tile[tx][rr];
        }
    }
}

// ---------------------------------------------------------------------------
// W table [NP=768][KP=736] bf16, row j: W[j][2m]=c_m cos(2pi m j/720),
// W[j][2m+1]=-c_m sin(...), c_0=c_360=1 else 2; zero-padded.
// ---------------------------------------------------------------------------
__global__ __launch_bounds__(256) void sht_make_w(__hip_bfloat16* __restrict__ W)
{
    const int idx = blockIdx.x * 256 + threadIdx.x;   // NP*KP total
    const int j = idx / KP;
    const int q = idx % KP;
    float v = 0.f;
    if (j < NLON && q < QT) {
        int m = q >> 1;
        float coef = (m == 0 || m == 360) ? 1.f : 2.f;
        int ph = (m * j) % 720;
        float ang = (float)ph * (float)(2.0 * M_PI / 720.0);
        float s, c;
        __sincosf(ang, &s, &c);
        v = (q & 1) ? (-coef * s) : (coef * c);
    }
    W[idx] = __float2bfloat16(v);
}

// ---------------------------------------------------------------------------
// Stage 2 GEMM: out[R][j] = sum_q interT[R][q] * W[j][q]
// BM=BN=128, BK=32, 256 threads = 4 waves (2x2), wave tile 64x64
// (4x4 fragments of mfma_f32_16x16x32_bf16), reg-staged LDS w/ prefetch.
// ---------------------------------------------------------------------------
__global__ __launch_bounds__(256) void sht_gemm(
    const __hip_bfloat16* __restrict__ A,   // [MT][KP]
    const __hip_bfloat16* __restrict__ W,   // [NP][KP]
    float* __restrict__ out)                // [MT][NLON]
{
    __shared__ __align__(16) __hip_bfloat16 As[BM * BK];
    __shared__ __align__(16) __hip_bfloat16 Bs[BN * BK];
    const int t  = threadIdx.x;
    const int R0 = blockIdx.x * BM;
    const int J0 = blockIdx.y * BN;

    // staging: chunk i in [0,512): row=i>>2, k=(i&3)*8; thread does i=t, t+256
    const int rowA = t >> 2;
    const int kc   = (t & 3) * 8;
    const int gr0  = min(R0 + rowA,      MT - 1);
    const int gr1  = min(R0 + rowA + 64, MT - 1);
    const __hip_bfloat16* pa0 = A + (size_t)gr0 * KP + kc;
    const __hip_bfloat16* pa1 = A + (size_t)gr1 * KP + kc;
    const __hip_bfloat16* pb0 = W + (size_t)(J0 + rowA) * KP + kc;
    const __hip_bfloat16* pb1 = W + (size_t)(J0 + rowA + 64) * KP + kc;

    const int lane = t & 63;
    const int wave = t >> 6;
    const int wm = (wave >> 1) * 64;
    const int wn = (wave & 1) * 64;
    const int fr = lane & 15;
    const int kg = (lane >> 4) * 8;

    f32x4 acc[4][4];
    const f32x4 zero = {0.f, 0.f, 0.f, 0.f};
    #pragma unroll
    for (int i = 0; i < 4; ++i)
        #pragma unroll
        for (int j = 0; j < 4; ++j) acc[i][j] = zero;

    short8 va0 = *(const short8*)pa0;
    short8 va1 = *(const short8*)pa1;
    short8 vb0 = *(const short8*)pb0;
    short8 vb1 = *(const short8*)pb1;

    for (int kt = 0; kt < KP / BK; ++kt) {
        __syncthreads();   // previous iteration's LDS reads done
        *(short8*)&As[t * 8]        = va0;
        *(short8*)&As[t * 8 + 2048] = va1;
        *(short8*)&Bs[t * 8]        = vb0;
        *(short8*)&Bs[t * 8 + 2048] = vb1;
        __syncthreads();

        if (kt + 1 < KP / BK) {
            const int ko = (kt + 1) * BK;
            va0 = *(const short8*)(pa0 + ko);
            va1 = *(const short8*)(pa1 + ko);
            vb0 = *(const short8*)(pb0 + ko);
            vb1 = *(const short8*)(pb1 + ko);
        }

        short8 af[4], bg[4];
        #pragma unroll
        for (int i = 0; i < 4; ++i)
            af[i] = *(const short8*)&As[(wm + i * 16 + fr) * BK + kg];
        #pragma unroll
        for (int i = 0; i < 4; ++i)
            bg[i] = *(const short8*)&Bs[(wn + i * 16 + fr) * BK + kg];

        #pragma unroll
        for (int mi = 0; mi < 4; ++mi)
            #pragma unroll
            for (int ni = 0; ni < 4; ++ni)
                acc[mi][ni] = __builtin_amdgcn_mfma_f32_16x16x32_bf16(
                    af[mi], bg[ni], acc[mi][ni], 0, 0, 0);
    }

    const int orow = (lane >> 4) * 4;
    #pragma unroll
    for (int mi = 0; mi < 4; ++mi) {
        #pragma unroll
        for (int ni = 0; ni < 4; ++ni) {
            #pragma unroll
            for (int r = 0; r < 4; ++r) {
                int row = R0 + wm + mi * 16 + orow + r;
                int col = J0 + wn + ni * 16 + fr;
                if (row < MT && col < NLON)
                    out[(size_t)row * NLON + col] = acc[mi][ni][r];
            }
        }
    }
}

// ---------------------------------------------------------------------------
extern "C" void kernel_launch(void* const* d_in, const int* in_sizes, int n_in,
                              void* d_out, int out_size, void* d_ws, size_t ws_size,
                              hipStream_t stream)
{
    const float* x    = (const float*)d_in[0];
    const float* dpct = (const float*)d_in[1];
    float* out        = (float*)d_out;

    char* ws = (char*)d_ws;
    __hip_bfloat16* interQ = (__hip_bfloat16*)ws;                     // [722][23104]  33.36 MB
    __hip_bfloat16* interT = (__hip_bfloat16*)(ws + (size_t)QT * MT * 2); // [23104][736] 34.01 MB
    __hip_bfloat16* Wt     = (__hip_bfloat16*)ws;                     // [768][736] 1.13 MB,
    // overlaps interQ -- written only AFTER sht_transpose has consumed interQ.

    dim3 g1(MMAX, BC / 8);
    sht_stage1<<<g1, 384, 0, stream>>>(x, dpct, interQ);

    dim3 gt(MT / 64, 12);
    sht_transpose<<<gt, 256, 0, stream>>>(interQ, interT);

    sht_make_w<<<(NP * KP) / 256, 256, 0, stream>>>(Wt);

    dim3 gg((MT + BM - 1) / BM, NP / BN);
    sht_gemm<<<gg, 256, 0, stream>>>(interT, Wt, out);
}

// Round 3
// 351.713 us; speedup vs baseline: 3.2477x; 2.4916x over previous
//
#include <hip/hip_runtime.h>
#include <hip/hip_bf16.h>
#include <math.h>

#define LMAX 360
#define MMAX 361
#define NLAT 361
#define NLON 720
#define BC   32
#define MT   (BC*2*NLAT)   // 23104 rows
#define QT   722           // valid K (2*MMAX) for stage-2 GEMM
#define KP   736           // stage-2 padded K = 23*32
#define NP   768           // stage-2 padded N
#define BM   128
#define BN   128
#define BK   32

typedef __attribute__((ext_vector_type(8))) short short8;
typedef __attribute__((ext_vector_type(4))) float f32x4;

// ---------------------------------------------------------------------------
// prep_x: x (fp32, [bc][f][l][m][ri]) -> xT bf16 [m][src*32+bc][l], src=f*2+ri
// rows are 360 bf16 = 720 B (16B-aligned). l<360 only.
// ---------------------------------------------------------------------------
__global__ __launch_bounds__(256) void sht_prep_x(
    const float* __restrict__ x, __hip_bfloat16* __restrict__ xT)
{
    const int m0  = blockIdx.x * 32;
    const int l0  = blockIdx.y * 32;
    const int bcf = blockIdx.z;
    const int bc = bcf >> 1, f = bcf & 1;
    __shared__ float2 tile[32][33];
    const float2* __restrict__ x2 = (const float2*)x;
    const int tm = threadIdx.x & 31, tl0 = threadIdx.x >> 5;

    for (int it = 0; it < 4; ++it) {
        int l  = l0 + tl0 + it * 8;
        int mm = m0 + tm;
        float2 v = make_float2(0.f, 0.f);
        if (l < LMAX && mm < MMAX)
            v = x2[((size_t)(bc * 2 + f) * LMAX + l) * MMAX + mm];
        tile[tl0 + it * 8][tm] = v;
    }
    __syncthreads();

    const int tlw = threadIdx.x & 31, tmw0 = threadIdx.x >> 5;
    const int l = l0 + tlw;
    if (l >= LMAX) return;
    for (int it = 0; it < 4; ++it) {
        int mm = m0 + tmw0 + it * 8;
        if (mm >= MMAX) continue;
        float2 v = tile[tlw][tmw0 + it * 8];
        size_t mb = (size_t)mm * (128 * LMAX);
        xT[mb + (size_t)((f * 2 + 0) * 32 + bc) * LMAX + l] = __float2bfloat16(v.x);
        xT[mb + (size_t)((f * 2 + 1) * 32 + bc) * LMAX + l] = __float2bfloat16(v.y);
    }
}

// ---------------------------------------------------------------------------
// gemm1: per-m MFMA GEMM.  D[k][combo] = sum_{l'} A[k][l'] * B[combo][l']
// K = 768 = two 384-padded halves (d0, d1).  Block: (m, h) h=M-half of 192 k.
// A = dpct (fp32, [p][m][l][k], k contig) -> transposed+cvt into LDS [k][l].
// B = xT rows with per-(half,plane) source/sign:
//   srl=[+x0r|-x1i]  sim=[+x0i|+x1r]  trl=[-x1r|-x0i]  tim=[-x1i|+x0r]
// Output interQ[2m+ri][(bc*2+t)*361+k] bf16.
// ---------------------------------------------------------------------------
__global__ __launch_bounds__(256, 2) void sht_gemm1(
    const float* __restrict__ dpct, const __hip_bfloat16* __restrict__ xT,
    __hip_bfloat16* __restrict__ interQ)
{
    const int m  = blockIdx.x;
    const int h  = blockIdx.y;
    const int k0 = h * 192;

    __shared__ __align__(16) __hip_bfloat16 Als[192 * 40];  // [k][l], stride 40
    __shared__ __align__(16) __hip_bfloat16 Bls[128 * 40];  // [combo][l], stride 40

    const int t = threadIdx.x;
    // A staging: (l = t&31, kq = t>>5), 6 iters cover 192 k in quads
    const int al  = t & 31;
    const int akq = t >> 5;
    // B staging: c = t>>1, osub = (t&1)*2 + i
    const int brow = t >> 1;
    const int bo2  = (t & 1) * 2;

    const int lane = t & 63;
    const int wave = t >> 6;
    const int wm = (wave >> 1) * 96;   // 6 M-frags
    const int wn = (wave & 1) * 64;    // 4 N-frags
    const int fr = lane & 15;
    const int kg = (lane >> 4) * 8;

    // B source/sign LUT indexed [half*4 + plane]
    const int    srcT[8] = {0, 1, 2, 3, 3, 2, 1, 0};
    const unsigned short sgnT[8] = {0, 0, 0x8000, 0x8000, 0x8000, 0, 0x8000, 0};

    f32x4 acc[6][4];
    const f32x4 zero = {0.f, 0.f, 0.f, 0.f};
    #pragma unroll
    for (int i = 0; i < 6; ++i)
        #pragma unroll
        for (int j = 0; j < 4; ++j) acc[i][j] = zero;

    float4 apf[6];
    short8 bpf[2];

    const int plane = brow >> 5;
    const int bcq   = brow & 31;

    // ---- load helpers (manually inlined via lambdas) ----
    auto loadA = [&](int ks) {
        int half = ks / 12;
        int lsub = (ks % 12) * 32;
        int lg   = lsub + al;               // 0..383
        bool lval = (lg < LMAX);
        size_t base = (((size_t)half * MMAX + m) * LMAX + (lval ? lg : 0)) * NLAT;
        #pragma unroll
        for (int it = 0; it < 6; ++it) {
            int kl  = (akq + 8 * it) * 4;
            int kgl = k0 + kl;
            if (!lval) {
                apf[it] = make_float4(0.f, 0.f, 0.f, 0.f);
            } else if (kgl + 3 <= 360) {
                apf[it] = *(const float4*)&dpct[base + kgl];
            } else {
                float4 v;
                v.x = (kgl + 0 <= 360) ? dpct[base + kgl + 0] : 0.f;
                v.y = (kgl + 1 <= 360) ? dpct[base + kgl + 1] : 0.f;
                v.z = (kgl + 2 <= 360) ? dpct[base + kgl + 2] : 0.f;
                v.w = 0.f;
                apf[it] = v;
            }
        }
    };

    auto loadB = [&](int ks) {
        int half = ks / 12;
        int lsub = (ks % 12) * 32;
        int src  = srcT[half * 4 + plane];
        unsigned short sg = sgnT[half * 4 + plane];
        #pragma unroll
        for (int i = 0; i < 2; ++i) {
            int osub = bo2 + i;
            int loff = lsub + osub * 8;
            short8 v;
            if (loff < LMAX) {
                v = *(const short8*)&xT[(size_t)m * (128 * LMAX) +
                                        (size_t)(src * 32 + bcq) * LMAX + loff];
                if (sg) {
                    #pragma unroll
                    for (int e = 0; e < 8; ++e) v[e] = v[e] ^ (short)0x8000;
                }
            } else {
                #pragma unroll
                for (int e = 0; e < 8; ++e) v[e] = 0;
            }
            bpf[i] = v;
        }
    };

    loadA(0);
    loadB(0);

    for (int ks = 0; ks < 24; ++ks) {
        __syncthreads();
        // write LDS from prefetch regs
        #pragma unroll
        for (int it = 0; it < 6; ++it) {
            int kl = (akq + 8 * it) * 4;
            Als[(kl + 0) * 40 + al] = __float2bfloat16(apf[it].x);
            Als[(kl + 1) * 40 + al] = __float2bfloat16(apf[it].y);
            Als[(kl + 2) * 40 + al] = __float2bfloat16(apf[it].z);
            Als[(kl + 3) * 40 + al] = __float2bfloat16(apf[it].w);
        }
        *(short8*)&Bls[brow * 40 + (bo2 + 0) * 8] = bpf[0];
        *(short8*)&Bls[brow * 40 + (bo2 + 1) * 8] = bpf[1];
        __syncthreads();

        if (ks + 1 < 24) { loadA(ks + 1); loadB(ks + 1); }

        short8 af[6], bg[4];
        #pragma unroll
        for (int mi = 0; mi < 6; ++mi)
            af[mi] = *(const short8*)&Als[(wm + mi * 16 + fr) * 40 + kg];
        #pragma unroll
        for (int ni = 0; ni < 4; ++ni)
            bg[ni] = *(const short8*)&Bls[(wn + ni * 16 + fr) * 40 + kg];

        #pragma unroll
        for (int mi = 0; mi < 6; ++mi)
            #pragma unroll
            for (int ni = 0; ni < 4; ++ni)
                acc[mi][ni] = __builtin_amdgcn_mfma_f32_16x16x32_bf16(
                    af[mi], bg[ni], acc[mi][ni], 0, 0, 0);
    }

    // store: k = k0 + wm + mi*16 + (lane>>4)*4 + r ; combo c = wn + ni*16 + fr
    #pragma unroll
    for (int mi = 0; mi < 6; ++mi) {
        int kr = k0 + wm + mi * 16 + (lane >> 4) * 4;
        #pragma unroll
        for (int ni = 0; ni < 4; ++ni) {
            int c = wn + ni * 16 + fr;
            int pl = c >> 5, bc = c & 31;
            int ri = pl & 1, tt = pl >> 1;
            size_t qb = (size_t)(2 * m + ri) * MT + (size_t)(bc * 2 + tt) * NLAT;
            #pragma unroll
            for (int r = 0; r < 4; ++r) {
                int k = kr + r;
                if (k < NLAT)
                    interQ[qb + k] = __float2bfloat16(acc[mi][ni][r]);
            }
        }
    }
}

// ---------------------------------------------------------------------------
// Transpose interQ [722][23104] -> interT [23104][736] (zero K-pad)
// ---------------------------------------------------------------------------
__global__ __launch_bounds__(256) void sht_transpose(
    const __hip_bfloat16* __restrict__ inQ, __hip_bfloat16* __restrict__ outT)
{
    __shared__ __hip_bfloat16 tile[64][65];
    const int R0 = blockIdx.x * 64;
    const int q0 = blockIdx.y * 64;
    const int tx = threadIdx.x & 63;
    const int ty = threadIdx.x >> 6;
    const __hip_bfloat16 zv = __float2bfloat16(0.f);

    for (int qq = ty; qq < 64; qq += 4) {
        int q = q0 + qq;
        tile[qq][tx] = (q < QT) ? inQ[(size_t)q * MT + R0 + tx] : zv;
    }
    __syncthreads();
    if (q0 + tx < KP) {
        for (int rr = ty; rr < 64; rr += 4) {
            outT[(size_t)(R0 + rr) * KP + q0 + tx] = tile[tx][rr];
        }
    }
}

// ---------------------------------------------------------------------------
// W table [NP=768][KP=736] bf16
// ---------------------------------------------------------------------------
__global__ __launch_bounds__(256) void sht_make_w(__hip_bfloat16* __restrict__ W)
{
    const int idx = blockIdx.x * 256 + threadIdx.x;
    const int j = idx / KP;
    const int q = idx % KP;
    float v = 0.f;
    if (j < NLON && q < QT) {
        int m = q >> 1;
        float coef = (m == 0 || m == 360) ? 1.f : 2.f;
        int ph = (m * j) % 720;
        float ang = (float)ph * (float)(2.0 * M_PI / 720.0);
        float s, c;
        __sincosf(ang, &s, &c);
        v = (q & 1) ? (-coef * s) : (coef * c);
    }
    W[idx] = __float2bfloat16(v);
}

// ---------------------------------------------------------------------------
// Stage 2 GEMM (unchanged, proven): out[R][j] = sum_q interT[R][q] * W[j][q]
// ---------------------------------------------------------------------------
__global__ __launch_bounds__(256) void sht_gemm(
    const __hip_bfloat16* __restrict__ A,   // [MT][KP]
    const __hip_bfloat16* __restrict__ W,   // [NP][KP]
    float* __restrict__ out)                // [MT][NLON]
{
    __shared__ __align__(16) __hip_bfloat16 As[BM * BK];
    __shared__ __align__(16) __hip_bfloat16 Bs[BN * BK];
    const int t  = threadIdx.x;
    const int R0 = blockIdx.x * BM;
    const int J0 = blockIdx.y * BN;

    const int rowA = t >> 2;
    const int kc   = (t & 3) * 8;
    const int gr0  = min(R0 + rowA,      MT - 1);
    const int gr1  = min(R0 + rowA + 64, MT - 1);
    const __hip_bfloat16* pa0 = A + (size_t)gr0 * KP + kc;
    const __hip_bfloat16* pa1 = A + (size_t)gr1 * KP + kc;
    const __hip_bfloat16* pb0 = W + (size_t)(J0 + rowA) * KP + kc;
    const __hip_bfloat16* pb1 = W + (size_t)(J0 + rowA + 64) * KP + kc;

    const int lane = t & 63;
    const int wave = t >> 6;
    const int wm = (wave >> 1) * 64;
    const int wn = (wave & 1) * 64;
    const int fr = lane & 15;
    const int kg = (lane >> 4) * 8;

    f32x4 acc[4][4];
    const f32x4 zero = {0.f, 0.f, 0.f, 0.f};
    #pragma unroll
    for (int i = 0; i < 4; ++i)
        #pragma unroll
        for (int j = 0; j < 4; ++j) acc[i][j] = zero;

    short8 va0 = *(const short8*)pa0;
    short8 va1 = *(const short8*)pa1;
    short8 vb0 = *(const short8*)pb0;
    short8 vb1 = *(const short8*)pb1;

    for (int kt = 0; kt < KP / BK; ++kt) {
        __syncthreads();
        *(short8*)&As[t * 8]        = va0;
        *(short8*)&As[t * 8 + 2048] = va1;
        *(short8*)&Bs[t * 8]        = vb0;
        *(short8*)&Bs[t * 8 + 2048] = vb1;
        __syncthreads();

        if (kt + 1 < KP / BK) {
            const int ko = (kt + 1) * BK;
            va0 = *(const short8*)(pa0 + ko);
            va1 = *(const short8*)(pa1 + ko);
            vb0 = *(const short8*)(pb0 + ko);
            vb1 = *(const short8*)(pb1 + ko);
        }

        short8 af[4], bg[4];
        #pragma unroll
        for (int i = 0; i < 4; ++i)
            af[i] = *(const short8*)&As[(wm + i * 16 + fr) * BK + kg];
        #pragma unroll
        for (int i = 0; i < 4; ++i)
            bg[i] = *(const short8*)&Bs[(wn + i * 16 + fr) * BK + kg];

        #pragma unroll
        for (int mi = 0; mi < 4; ++mi)
            #pragma unroll
            for (int ni = 0; ni < 4; ++ni)
                acc[mi][ni] = __builtin_amdgcn_mfma_f32_16x16x32_bf16(
                    af[mi], bg[ni], acc[mi][ni], 0, 0, 0);
    }

    const int orow = (lane >> 4) * 4;
    #pragma unroll
    for (int mi = 0; mi < 4; ++mi) {
        #pragma unroll
        for (int ni = 0; ni < 4; ++ni) {
            #pragma unroll
            for (int r = 0; r < 4; ++r) {
                int row = R0 + wm + mi * 16 + orow + r;
                int col = J0 + wn + ni * 16 + fr;
                if (row < MT && col < NLON)
                    out[(size_t)row * NLON + col] = acc[mi][ni][r];
            }
        }
    }
}

// ---------------------------------------------------------------------------
// Workspace layout (total 67,371,264 B == proven available in R1/R2):
//   region A [0, 34,009,088):  xT (33,269,760 B)  then interT (34,009,088 B)
//   region B [34,009,088, 67,371,264):  interQ (33,362,176 B) then W (1,130,496 B)
// Liveness: xT:[prep->gemm1]  interQ:[gemm1->transpose]  interT:[transpose->gemm2]
//           W:[make_w->gemm2] (interQ dead by then)
// ---------------------------------------------------------------------------
extern "C" void kernel_launch(void* const* d_in, const int* in_sizes, int n_in,
                              void* d_out, int out_size, void* d_ws, size_t ws_size,
                              hipStream_t stream)
{
    const float* x    = (const float*)d_in[0];
    const float* dpct = (const float*)d_in[1];
    float* out        = (float*)d_out;

    char* ws = (char*)d_ws;
    __hip_bfloat16* xT     = (__hip_bfloat16*)ws;
    __hip_bfloat16* interT = (__hip_bfloat16*)ws;
    __hip_bfloat16* interQ = (__hip_bfloat16*)(ws + 34009088);
    __hip_bfloat16* Wt     = (__hip_bfloat16*)(ws + 34009088);

    dim3 gp(12, 12, 64);
    sht_prep_x<<<gp, 256, 0, stream>>>(x, xT);

    dim3 g1(MMAX, 2);
    sht_gemm1<<<g1, 256, 0, stream>>>(dpct, xT, interQ);

    dim3 gt(MT / 64, 12);
    sht_transpose<<<gt, 256, 0, stream>>>(interQ, interT);

    sht_make_w<<<(NP * KP) / 256, 256, 0, stream>>>(Wt);

    dim3 gg((MT + BM - 1) / BM, NP / BN);
    sht_gemm<<<gg, 256, 0, stream>>>(interT, Wt, out);
}

// Round 4
// 283.394 us; speedup vs baseline: 4.0307x; 1.2411x over previous
//
#include <hip/hip_runtime.h>
#include <hip/hip_bf16.h>
#include <math.h>

#define LMAX 360
#define MMAX 361
#define NLAT 361
#define NLON 720
#define BC   32
#define MT   (BC*2*NLAT)   // 23104 rows
#define QT   722           // valid K (2*MMAX) for stage-2 GEMM
#define KP   736           // stage-2 padded K = 23*32
#define NP   768           // stage-2 padded N
#define BM   128
#define BN   128
#define BK   32

typedef __attribute__((ext_vector_type(8))) short short8;
typedef __attribute__((ext_vector_type(4))) short short4v;
typedef __attribute__((ext_vector_type(4))) float f32x4;

static __device__ __forceinline__ short f2bf(float v) {
    __hip_bfloat16 h = __float2bfloat16(v);
    return *reinterpret_cast<short*>(&h);
}

// ---------------------------------------------------------------------------
// prep_x: x (fp32, [bc][f][l][m][ri]) -> xT bf16 [m][src*32+bc][l], src=f*2+ri
// 64l x 32m LDS tile; writes are short8 runs along l (coalesced).
// ---------------------------------------------------------------------------
__global__ __launch_bounds__(256) void sht_prep_x(
    const float* __restrict__ x, __hip_bfloat16* __restrict__ xT)
{
    const int m0 = blockIdx.x * 32;
    const int l0 = blockIdx.y * 64;
    const int bc = blockIdx.z >> 1, f = blockIdx.z & 1;
    __shared__ float2 tile[64][33];
    const float2* __restrict__ x2 = (const float2*)x;
    const int t = threadIdx.x;
    const int rm = t & 31, rl = t >> 5;

    #pragma unroll
    for (int r = 0; r < 8; ++r) {
        int l  = l0 + rl + r * 8;
        int mm = m0 + rm;
        float2 v = make_float2(0.f, 0.f);
        if (l < LMAX && mm < MMAX)
            v = x2[((size_t)(bc * 2 + f) * LMAX + l) * MMAX + mm];
        tile[rl + r * 8][rm] = v;
    }
    __syncthreads();

    const int tm = t >> 3, lg = t & 7;
    const int m = m0 + tm;
    if (m >= MMAX) return;
    const int lw = l0 + lg * 8;
    if (lw >= LMAX) return;          // 360 is granule-aligned (45*8)

    short8 re, im;
    #pragma unroll
    for (int e = 0; e < 8; ++e) {
        float2 v = tile[lg * 8 + e][tm];
        re[e] = f2bf(v.x);
        im[e] = f2bf(v.y);
    }
    size_t mb = (size_t)m * (128 * LMAX);
    *(short8*)((short*)xT + mb + (size_t)((f * 2 + 0) * 32 + bc) * LMAX + lw) = re;
    *(short8*)((short*)xT + mb + (size_t)((f * 2 + 1) * 32 + bc) * LMAX + lw) = im;
}

// ---------------------------------------------------------------------------
// gemm1: per-m MFMA GEMM.  D[k][combo] = sum_{l'} A[k][l'] * B[combo][l']
// K = 768 = two 384-padded halves (d0, d1); 12 steps of BKL=64.
// A from dpct fp32 [l][k]: coalesced float4 loads (lane->k), 4x4 register
// transpose, ds_write_b64 into swizzled LDS [k][l] (granule XOR (k&7)).
// B from xT bf16 [combo][l]: short8 granules, same swizzle (XOR (c&7)).
// Fragment reads apply the same XOR -> logical mapping identical to R3.
// ---------------------------------------------------------------------------
__global__ __launch_bounds__(256, 2) void sht_gemm1(
    const float* __restrict__ dpct, const __hip_bfloat16* __restrict__ xT,
    __hip_bfloat16* __restrict__ interQ)
{
    const int m  = blockIdx.x;
    const int K0 = blockIdx.y * 192;

    __shared__ __align__(16) char AlsB[192 * 128];   // [k][64l bf16], 128B rows
    __shared__ __align__(16) char BlsB[128 * 128];   // [c][64l bf16]

    const int t    = threadIdx.x;
    const int lane = t & 63;
    const int wave = t >> 6;
    const int wm = (wave >> 1) * 96;   // 6 M-frags
    const int wn = (wave & 1) * 64;    // 4 N-frags
    const int fr = lane & 15;
    const int lq = lane >> 4;

    // A staging task constants: 768 (kq,lb) tasks, 3 per thread
    int kqv[3], lbv[3];
    #pragma unroll
    for (int it = 0; it < 3; ++it) {
        int task = it * 256 + t;
        kqv[it] = task % 48;
        lbv[it] = task / 48;
    }
    // B staging: c = t>>1, granules g0B..g0B+3
    const int cB    = t >> 1;
    const int plane = cB >> 5, bcq = cB & 31;
    const int g0B   = (t & 1) * 4;

    const int            srcT[8] = {0, 1, 2, 3, 3, 2, 1, 0};
    const unsigned short sgnT[8] = {0, 0, 0x8000, 0x8000, 0x8000, 0, 0x8000, 0};

    f32x4 acc[6][4];
    const f32x4 zero = {0.f, 0.f, 0.f, 0.f};
    #pragma unroll
    for (int i = 0; i < 6; ++i)
        #pragma unroll
        for (int j = 0; j < 4; ++j) acc[i][j] = zero;

    float4 apf[3][4];
    short8 bpf[4];

    auto loadA = [&](int ks) {
        int p = ks / 6, l0 = (ks % 6) * 64;
        #pragma unroll
        for (int it = 0; it < 3; ++it) {
            int kg = K0 + kqv[it] * 4;
            size_t rb = (((size_t)p * MMAX + m) * LMAX) * (size_t)NLAT + kg;
            #pragma unroll
            for (int j = 0; j < 4; ++j) {
                int lg2 = l0 + lbv[it] * 4 + j;
                float4 v = make_float4(0.f, 0.f, 0.f, 0.f);
                if (lg2 < LMAX) {
                    const float* src = dpct + rb + (size_t)lg2 * NLAT;
                    if (kg + 3 <= 360) {
                        v = *(const float4*)src;
                    } else if (kg <= 360) {
                        v.x = src[0];
                        if (kg + 1 <= 360) v.y = src[1];
                        if (kg + 2 <= 360) v.z = src[2];
                    }
                }
                apf[it][j] = v;
            }
        }
    };

    auto loadB = [&](int ks) {
        int p = ks / 6, l0 = (ks % 6) * 64;
        int src = srcT[p * 4 + plane];
        short sg = (short)sgnT[p * 4 + plane];
        const short* bbase = (const short*)xT + (size_t)m * (128 * LMAX) +
                             (size_t)(src * 32 + bcq) * LMAX;
        #pragma unroll
        for (int i = 0; i < 4; ++i) {
            int g   = g0B + i;
            int lg2 = l0 + g * 8;
            short8 v;
            if (lg2 < LMAX) {
                v = *(const short8*)(bbase + lg2);
                #pragma unroll
                for (int e = 0; e < 8; ++e) v[e] ^= sg;
            } else {
                #pragma unroll
                for (int e = 0; e < 8; ++e) v[e] = 0;
            }
            bpf[i] = v;
        }
    };

    loadA(0);
    loadB(0);

    for (int ks = 0; ks < 12; ++ks) {
        __syncthreads();

        // A: 4x4 register transpose -> 4 ds_write_b64 per task
        #pragma unroll
        for (int it = 0; it < 3; ++it) {
            const int lb = lbv[it];
            const int gA = lb >> 1;
            const int ob = (lb & 1) << 3;
#define WRITE_A_ROW(JJ, E0, E1, E2, E3)                                        \
            {                                                                  \
                int kl = kqv[it] * 4 + JJ;                                     \
                short4v w;                                                     \
                w[0] = f2bf(E0); w[1] = f2bf(E1);                              \
                w[2] = f2bf(E2); w[3] = f2bf(E3);                              \
                *(short4v*)(AlsB + kl * 128 + ((gA ^ (kl & 7)) << 4) + ob) = w;\
            }
            WRITE_A_ROW(0, apf[it][0].x, apf[it][1].x, apf[it][2].x, apf[it][3].x)
            WRITE_A_ROW(1, apf[it][0].y, apf[it][1].y, apf[it][2].y, apf[it][3].y)
            WRITE_A_ROW(2, apf[it][0].z, apf[it][1].z, apf[it][2].z, apf[it][3].z)
            WRITE_A_ROW(3, apf[it][0].w, apf[it][1].w, apf[it][2].w, apf[it][3].w)
#undef WRITE_A_ROW
        }
        // B: full-granule b128 writes
        #pragma unroll
        for (int i = 0; i < 4; ++i) {
            int g = g0B + i;
            *(short8*)(BlsB + cB * 128 + ((g ^ (cB & 7)) << 4)) = bpf[i];
        }
        __syncthreads();

        if (ks < 11) { loadA(ks + 1); loadB(ks + 1); }

        #pragma unroll
        for (int kk = 0; kk < 2; ++kk) {
            short8 af[6], bg[4];
            const int g = kk * 4 + lq;
            #pragma unroll
            for (int mi = 0; mi < 6; ++mi) {
                int k = wm + mi * 16 + fr;
                af[mi] = *(const short8*)(AlsB + k * 128 + ((g ^ (k & 7)) << 4));
            }
            #pragma unroll
            for (int ni = 0; ni < 4; ++ni) {
                int c = wn + ni * 16 + fr;
                bg[ni] = *(const short8*)(BlsB + c * 128 + ((g ^ (c & 7)) << 4));
            }
            #pragma unroll
            for (int mi = 0; mi < 6; ++mi)
                #pragma unroll
                for (int ni = 0; ni < 4; ++ni)
                    acc[mi][ni] = __builtin_amdgcn_mfma_f32_16x16x32_bf16(
                        af[mi], bg[ni], acc[mi][ni], 0, 0, 0);
        }
    }

    // store: k = K0 + wm + mi*16 + lq*4 + r ; combo c = wn + ni*16 + fr
    #pragma unroll
    for (int mi = 0; mi < 6; ++mi) {
        int kr = K0 + wm + mi * 16 + lq * 4;
        #pragma unroll
        for (int ni = 0; ni < 4; ++ni) {
            int c = wn + ni * 16 + fr;
            int pl = c >> 5, bc = c & 31;
            int ri = pl & 1, tt = pl >> 1;
            size_t qb = (size_t)(2 * m + ri) * MT + (size_t)(bc * 2 + tt) * NLAT;
            #pragma unroll
            for (int r = 0; r < 4; ++r) {
                int k = kr + r;
                if (k < NLAT)
                    interQ[qb + k] = __float2bfloat16(acc[mi][ni][r]);
            }
        }
    }
}

// ---------------------------------------------------------------------------
// Transpose interQ [722][23104] -> interT [23104][736] (zero K-pad)
// ---------------------------------------------------------------------------
__global__ __launch_bounds__(256) void sht_transpose(
    const __hip_bfloat16* __restrict__ inQ, __hip_bfloat16* __restrict__ outT)
{
    __shared__ __hip_bfloat16 tile[64][65];
    const int R0 = blockIdx.x * 64;
    const int q0 = blockIdx.y * 64;
    const int tx = threadIdx.x & 63;
    const int ty = threadIdx.x >> 6;
    const __hip_bfloat16 zv = __float2bfloat16(0.f);

    for (int qq = ty; qq < 64; qq += 4) {
        int q = q0 + qq;
        tile[qq][tx] = (q < QT) ? inQ[(size_t)q * MT + R0 + tx] : zv;
    }
    __syncthreads();
    if (q0 + tx < KP) {
        for (int rr = ty; rr < 64; rr += 4) {
            outT[(size_t)(R0 + rr) * KP + q0 + tx] = tile[tx][rr];
        }
    }
}

// ---------------------------------------------------------------------------
// W table [NP=768][KP=736] bf16
// ---------------------------------------------------------------------------
__global__ __launch_bounds__(256) void sht_make_w(__hip_bfloat16* __restrict__ W)
{
    const int idx = blockIdx.x * 256 + threadIdx.x;
    const int j = idx / KP;
    const int q = idx % KP;
    float v = 0.f;
    if (j < NLON && q < QT) {
        int m = q >> 1;
        float coef = (m == 0 || m == 360) ? 1.f : 2.f;
        int ph = (m * j) % 720;
        float ang = (float)ph * (float)(2.0 * M_PI / 720.0);
        float s, c;
        __sincosf(ang, &s, &c);
        v = (q & 1) ? (-coef * s) : (coef * c);
    }
    W[idx] = __float2bfloat16(v);
}

// ---------------------------------------------------------------------------
// Stage 2 GEMM (unchanged, proven): out[R][j] = sum_q interT[R][q] * W[j][q]
// ---------------------------------------------------------------------------
__global__ __launch_bounds__(256) void sht_gemm(
    const __hip_bfloat16* __restrict__ A,   // [MT][KP]
    const __hip_bfloat16* __restrict__ W,   // [NP][KP]
    float* __restrict__ out)                // [MT][NLON]
{
    __shared__ __align__(16) __hip_bfloat16 As[BM * BK];
    __shared__ __align__(16) __hip_bfloat16 Bs[BN * BK];
    const int t  = threadIdx.x;
    const int R0 = blockIdx.x * BM;
    const int J0 = blockIdx.y * BN;

    const int rowA = t >> 2;
    const int kc   = (t & 3) * 8;
    const int gr0  = min(R0 + rowA,      MT - 1);
    const int gr1  = min(R0 + rowA + 64, MT - 1);
    const __hip_bfloat16* pa0 = A + (size_t)gr0 * KP + kc;
    const __hip_bfloat16* pa1 = A + (size_t)gr1 * KP + kc;
    const __hip_bfloat16* pb0 = W + (size_t)(J0 + rowA) * KP + kc;
    const __hip_bfloat16* pb1 = W + (size_t)(J0 + rowA + 64) * KP + kc;

    const int lane = t & 63;
    const int wave = t >> 6;
    const int wm = (wave >> 1) * 64;
    const int wn = (wave & 1) * 64;
    const int fr = lane & 15;
    const int kg = (lane >> 4) * 8;

    f32x4 acc[4][4];
    const f32x4 zero = {0.f, 0.f, 0.f, 0.f};
    #pragma unroll
    for (int i = 0; i < 4; ++i)
        #pragma unroll
        for (int j = 0; j < 4; ++j) acc[i][j] = zero;

    short8 va0 = *(const short8*)pa0;
    short8 va1 = *(const short8*)pa1;
    short8 vb0 = *(const short8*)pb0;
    short8 vb1 = *(const short8*)pb1;

    for (int kt = 0; kt < KP / BK; ++kt) {
        __syncthreads();
        *(short8*)&As[t * 8]        = va0;
        *(short8*)&As[t * 8 + 2048] = va1;
        *(short8*)&Bs[t * 8]        = vb0;
        *(short8*)&Bs[t * 8 + 2048] = vb1;
        __syncthreads();

        if (kt + 1 < KP / BK) {
            const int ko = (kt + 1) * BK;
            va0 = *(const short8*)(pa0 + ko);
            va1 = *(const short8*)(pa1 + ko);
            vb0 = *(const short8*)(pb0 + ko);
            vb1 = *(const short8*)(pb1 + ko);
        }

        short8 af[4], bg[4];
        #pragma unroll
        for (int i = 0; i < 4; ++i)
            af[i] = *(const short8*)&As[(wm + i * 16 + fr) * BK + kg];
        #pragma unroll
        for (int i = 0; i < 4; ++i)
            bg[i] = *(const short8*)&Bs[(wn + i * 16 + fr) * BK + kg];

        #pragma unroll
        for (int mi = 0; mi < 4; ++mi)
            #pragma unroll
            for (int ni = 0; ni < 4; ++ni)
                acc[mi][ni] = __builtin_amdgcn_mfma_f32_16x16x32_bf16(
                    af[mi], bg[ni], acc[mi][ni], 0, 0, 0);
    }

    const int orow = (lane >> 4) * 4;
    #pragma unroll
    for (int mi = 0; mi < 4; ++mi) {
        #pragma unroll
        for (int ni = 0; ni < 4; ++ni) {
            #pragma unroll
            for (int r = 0; r < 4; ++r) {
                int row = R0 + wm + mi * 16 + orow + r;
                int col = J0 + wn + ni * 16 + fr;
                if (row < MT && col < NLON)
                    out[(size_t)row * NLON + col] = acc[mi][ni][r];
            }
        }
    }
}

// ---------------------------------------------------------------------------
// Workspace layout (total 67,371,264 B — proven available):
//   region A [0, 34,009,088):  xT (33,269,760 B)  then interT (34,009,088 B)
//   region B [34,009,088, 67,371,264):  interQ (33,362,176 B) then W
// ---------------------------------------------------------------------------
extern "C" void kernel_launch(void* const* d_in, const int* in_sizes, int n_in,
                              void* d_out, int out_size, void* d_ws, size_t ws_size,
                              hipStream_t stream)
{
    const float* x    = (const float*)d_in[0];
    const float* dpct = (const float*)d_in[1];
    float* out        = (float*)d_out;

    char* ws = (char*)d_ws;
    __hip_bfloat16* xT     = (__hip_bfloat16*)ws;
    __hip_bfloat16* interT = (__hip_bfloat16*)ws;
    __hip_bfloat16* interQ = (__hip_bfloat16*)(ws + 34009088);
    __hip_bfloat16* Wt     = (__hip_bfloat16*)(ws + 34009088);

    dim3 gp(12, 6, 64);
    sht_prep_x<<<gp, 256, 0, stream>>>(x, xT);

    dim3 g1(MMAX, 2);
    sht_gemm1<<<g1, 256, 0, stream>>>(dpct, xT, interQ);

    dim3 gt(MT / 64, 12);
    sht_transpose<<<gt, 256, 0, stream>>>(interQ, interT);

    sht_make_w<<<(NP * KP) / 256, 256, 0, stream>>>(Wt);

    dim3 gg((MT + BM - 1) / BM, NP / BN);
    sht_gemm<<<gg, 256, 0, stream>>>(interT, Wt, out);
}